// Round 1
// baseline (588.990 us; speedup 1.0000x reference)
//
#include <hip/hip_runtime.h>
#include <hip/hip_bf16.h>

typedef short short8 __attribute__((ext_vector_type(8)));
typedef float float4v __attribute__((ext_vector_type(4)));

#define NIMG 32
#define CIN 256
#define COUT 256
#define HH 56
#define WW 56
#define HP 58
#define WP 58
#define PIXIMG (HH * WW)          /* 3136 */
#define TOTPIX (NIMG * PIXIMG)    /* 100352 */
#define OUTSTRIDE_N (COUT * PIXIMG)

static constexpr size_t XT_ELEMS = (size_t)NIMG * HP * WP * CIN; // 27,553,792 bf16
static constexpr size_t WT_ELEMS = (size_t)9 * COUT * CIN;       // 589,824 bf16

// fp32 -> bf16 bits, round-to-nearest-even (finite inputs only)
static __device__ __forceinline__ unsigned short f2bf(float f) {
    unsigned int u = __builtin_bit_cast(unsigned int, f);
    u = (u + 0x7fffu + ((u >> 16) & 1u)) >> 16;
    return (unsigned short)u;
}

// ---------------------------------------------------------------------------
// x (NCHW fp32) -> x_t[n][h'][w'][ic] bf16, h'/w' padded by 1 (halo pre-zeroed)
// ---------------------------------------------------------------------------
__global__ __launch_bounds__(256) void k_transpose(const float* __restrict__ x,
                                                   unsigned short* __restrict__ xt) {
    int b   = blockIdx.x;
    int icb = b & 3;            // 4 blocks of 64 ic
    int h   = (b >> 2) % HH;
    int n   = b / (4 * HH);
    __shared__ __align__(16) char lds[64 * 128]; // [w 64][ic 64] bf16, swizzled

    int t    = threadIdx.x;
    int w    = t & 63;
    int icl0 = t >> 6;          // 0..3
    if (w < WW) {
        const float* src = x + ((size_t)(n * CIN + icb * 64 + icl0) * HH + h) * WW + w;
#pragma unroll
        for (int j = 0; j < 16; ++j) {
            float v = src[(size_t)(j * 4) * PIXIMG];
            int icl = icl0 + j * 4;
            *(unsigned short*)(lds + w * 128 + ((icl * 2) ^ ((w & 7) << 4))) = f2bf(v);
        }
    }
    __syncthreads();
    int ic4 = t & 15;
    int wr  = t >> 4;
    unsigned short* dst = xt + (size_t)((n * HP + h + 1) * WP + 1) * CIN + icb * 64 + ic4 * 4;
#pragma unroll
    for (int p = 0; p < 4; ++p) {
        int w2 = wr + p * 16;
        if (w2 < WW) {
            uint2 v = *(const uint2*)(lds + w2 * 128 + ((ic4 * 8) ^ ((w2 & 7) << 4)));
            *(uint2*)(dst + (size_t)w2 * CIN) = v;
        }
    }
}

// ---------------------------------------------------------------------------
// wt[tap][oc][ic] = bf16(weight * mask)
// ---------------------------------------------------------------------------
__global__ __launch_bounds__(256) void k_prepw(const float* __restrict__ wgt,
                                               const float* __restrict__ msk,
                                               unsigned short* __restrict__ wt) {
    int t = blockIdx.x * 256 + threadIdx.x; // t = oc*256 + ic, 65536 threads
    const float* wp = wgt + (size_t)t * 9;
    const float* mp = msk + (size_t)t * 9;
#pragma unroll
    for (int tap = 0; tap < 9; ++tap)
        wt[(size_t)tap * (COUT * CIN) + t] = f2bf(wp[tap] * mp[tap]);
}

// ---------------------------------------------------------------------------
// Main conv: 9 shifted GEMMs. A = weights (M=oc), B = x_t pixels (N=pix).
// Block tile 128 oc x 128 pix, 4 waves (2x2), BK=64 ic, 16x16x32 bf16 MFMA.
// ---------------------------------------------------------------------------
__global__ __launch_bounds__(256) void k_conv(const unsigned short* __restrict__ xt,
                                              const unsigned short* __restrict__ wt,
                                              float* __restrict__ out) {
    __shared__ __align__(16) char ldsA[128 * 128]; // weights [oc 128][ic 64] bf16 swz
    __shared__ __align__(16) char ldsB[128 * 128]; // x       [pix 128][ic 64] bf16 swz

    const int t    = threadIdx.x;
    const int lane = t & 63;
    const int wid  = t >> 6;
    const int woc  = wid >> 1; // 0..1 : which 64-oc half
    const int wpx  = wid & 1;  // 0..1 : which 64-pix half
    const int bx    = blockIdx.x;
    const int ptile = bx >> 1; // 784 pixel tiles of 128
    const int ocb   = bx & 1;  // 2 oc halves of 128

    // staging mapping: each thread stages 4 rows x 8 ic (16B) for A and B
    const int icg  = t & 7;
    const int srow = t >> 3; // 0..31
    const int swzw = (srow & 7) << 4;

    const unsigned short* xbase[4];
#pragma unroll
    for (int mh = 0; mh < 4; ++mh) {
        int pg  = ptile * 128 + mh * 32 + srow;
        int n   = pg / PIXIMG;
        int rem = pg - n * PIXIMG;
        int h   = rem / WW;
        int w   = rem - h * WW;
        // x_t[h'][w'] holds x[h'-1][w'-1]; tap (dh,dw) adds (dh*WP+dw)*CIN
        xbase[mh] = xt + (size_t)((n * HP + h) * WP + w) * CIN + icg * 8;
    }
    const unsigned short* wbase = wt + (size_t)(ocb * 128) * CIN + icg * 8;

    int soff[4];
#pragma unroll
    for (int q = 0; q < 4; ++q)
        soff[q] = (q * 32 + srow) * 128 + ((icg * 16) ^ swzw);

    // fragment read offsets
    const int l15  = lane & 15;
    const int lg   = lane >> 4;
    const int swzf = (lane & 7) << 4;
    int colk[2];
    colk[0] = (lg * 16) ^ swzf;
    colk[1] = (64 + lg * 16) ^ swzf;
    int rowA[4], rowB[4];
#pragma unroll
    for (int i = 0; i < 4; ++i) {
        rowA[i] = (woc * 64 + i * 16 + l15) * 128;
        rowB[i] = (wpx * 64 + i * 16 + l15) * 128;
    }

    float4v acc[4][4];
#pragma unroll
    for (int i = 0; i < 4; ++i) {
#pragma unroll
        for (int j = 0; j < 4; ++j)
            acc[i][j] = (float4v){0.f, 0.f, 0.f, 0.f};
    }

#pragma unroll 1
    for (int tap = 0; tap < 9; ++tap) {
        const int dh = tap / 3, dw = tap - dh * 3;
        const size_t xtoff = (size_t)(dh * WP + dw) * CIN;
        const unsigned short* wtap = wbase + (size_t)tap * (COUT * CIN);
#pragma unroll
        for (int ics = 0; ics < 4; ++ics) {
            const int ico = ics * 64;
            uint4 av[4], bv[4];
#pragma unroll
            for (int q = 0; q < 4; ++q)
                av[q] = *(const uint4*)(wtap + (size_t)(q * 32 + srow) * CIN + ico);
#pragma unroll
            for (int q = 0; q < 4; ++q)
                bv[q] = *(const uint4*)(xbase[q] + xtoff + ico);
            __syncthreads(); // previous compute phase done before overwrite
#pragma unroll
            for (int q = 0; q < 4; ++q) {
                *(uint4*)(ldsA + soff[q]) = av[q];
                *(uint4*)(ldsB + soff[q]) = bv[q];
            }
            __syncthreads(); // tiles visible
#pragma unroll
            for (int kk = 0; kk < 2; ++kk) {
                short8 af[4], bfr[4];
#pragma unroll
                for (int oi = 0; oi < 4; ++oi)
                    af[oi] = *(const short8*)(ldsA + rowA[oi] + colk[kk]);
#pragma unroll
                for (int pi = 0; pi < 4; ++pi)
                    bfr[pi] = *(const short8*)(ldsB + rowB[pi] + colk[kk]);
#pragma unroll
                for (int oi = 0; oi < 4; ++oi) {
#pragma unroll
                    for (int pi = 0; pi < 4; ++pi)
                        acc[oi][pi] = __builtin_amdgcn_mfma_f32_16x16x32_bf16(
                            af[oi], bfr[pi], acc[oi][pi], 0, 0, 0);
                }
            }
        }
    }

    // epilogue: D col (lane&15) = pixel -> coalesced 64B-segment stores
    float* obase[4];
#pragma unroll
    for (int pi = 0; pi < 4; ++pi) {
        int pg  = ptile * 128 + wpx * 64 + pi * 16 + l15;
        int n   = pg / PIXIMG;
        int rem = pg - n * PIXIMG;
        obase[pi] = out + (size_t)n * OUTSTRIDE_N + rem + (size_t)(ocb * 128 + woc * 64) * PIXIMG;
    }
#pragma unroll
    for (int oi = 0; oi < 4; ++oi) {
#pragma unroll
        for (int pi = 0; pi < 4; ++pi) {
#pragma unroll
            for (int r = 0; r < 4; ++r)
                obase[pi][(size_t)(oi * 16 + lg * 4 + r) * PIXIMG] = acc[oi][pi][r];
        }
    }
}

// ---------------------------------------------------------------------------
// Fallback (ws too small): direct fp32 conv, slow but correct
// ---------------------------------------------------------------------------
__global__ __launch_bounds__(256) void k_naive(const float* __restrict__ x,
                                               const float* __restrict__ wg,
                                               const float* __restrict__ mk,
                                               float* __restrict__ out, int total) {
    int idx = blockIdx.x * 256 + threadIdx.x;
    if (idx >= total) return;
    int w  = idx % WW;
    int h  = (idx / WW) % HH;
    int oc = (idx / PIXIMG) % COUT;
    int n  = idx / (COUT * PIXIMG);
    float s = 0.f;
    for (int ic = 0; ic < CIN; ++ic) {
        const float* xp = x + (size_t)(n * CIN + ic) * PIXIMG;
        const float* wp = wg + (size_t)(oc * CIN + ic) * 9;
        const float* mp = mk + (size_t)(oc * CIN + ic) * 9;
#pragma unroll
        for (int kh = 0; kh < 3; ++kh) {
            int hy = h + kh - 1;
            if ((unsigned)hy >= HH) continue;
#pragma unroll
            for (int kw = 0; kw < 3; ++kw) {
                int wx = w + kw - 1;
                if ((unsigned)wx >= WW) continue;
                s += xp[hy * WW + wx] * wp[kh * 3 + kw] * mp[kh * 3 + kw];
            }
        }
    }
    out[idx] = s;
}

extern "C" void kernel_launch(void* const* d_in, const int* in_sizes, int n_in,
                              void* d_out, int out_size, void* d_ws, size_t ws_size,
                              hipStream_t stream) {
    const float* x  = (const float*)d_in[0];
    const float* wg = (const float*)d_in[1];
    const float* mk = (const float*)d_in[2];
    float* out = (float*)d_out;

    size_t need = XT_ELEMS * 2 + WT_ELEMS * 2 + 256;
    if (ws_size < need) {
        int total = NIMG * COUT * PIXIMG;
        k_naive<<<(total + 255) / 256, 256, 0, stream>>>(x, wg, mk, out, total);
        return;
    }

    unsigned short* xt = (unsigned short*)d_ws;
    unsigned short* wt = (unsigned short*)((char*)d_ws + XT_ELEMS * 2);

    hipMemsetAsync(d_ws, 0, XT_ELEMS * 2, stream); // zero padded halo
    k_transpose<<<NIMG * HH * 4, 256, 0, stream>>>(x, xt);
    k_prepw<<<(COUT * CIN) / 256, 256, 0, stream>>>(wg, mk, wt);
    k_conv<<<(TOTPIX / 128) * 2, 256, 0, stream>>>(xt, wt, out);
}

// Round 2
// 178.701 us; speedup vs baseline: 3.2959x; 3.2959x over previous
//
#include <hip/hip_runtime.h>
#include <hip/hip_bf16.h>

typedef short short8 __attribute__((ext_vector_type(8)));
typedef float float4v __attribute__((ext_vector_type(4)));

#define NIMG 32
#define CIN 256
#define COUT 256
#define HH 56
#define WW 56
#define HP 58
#define WP 58
#define PIXIMG (HH * WW)          /* 3136 */
#define TOTPIX (NIMG * PIXIMG)    /* 100352 */
#define OUTSTRIDE_N (COUT * PIXIMG)

static constexpr size_t XT_ELEMS = (size_t)NIMG * HP * WP * CIN; // bf16
static constexpr size_t WT_ELEMS = (size_t)9 * COUT * CIN;       // bf16

// fp32 -> bf16 bits, round-to-nearest-even (finite inputs only)
static __device__ __forceinline__ unsigned short f2bf(float f) {
    unsigned int u = __builtin_bit_cast(unsigned int, f);
    u = (u + 0x7fffu + ((u >> 16) & 1u)) >> 16;
    return (unsigned short)u;
}

// async global(16B/lane) -> LDS (wave-uniform base + lane*16)
static __device__ __forceinline__ void gl16(const unsigned short* g, char* l) {
    __builtin_amdgcn_global_load_lds(
        (const __attribute__((address_space(1))) void*)g,
        (__attribute__((address_space(3))) void*)l, 16, 0, 0);
}

// ---------------------------------------------------------------------------
// x (NCHW fp32) -> x_t[n][h'][w'][ic] bf16, h'/w' padded by 1 (halo pre-zeroed)
// ---------------------------------------------------------------------------
__global__ __launch_bounds__(256) void k_transpose(const float* __restrict__ x,
                                                   unsigned short* __restrict__ xt) {
    int b   = blockIdx.x;
    int icb = b & 3;            // 4 blocks of 64 ic
    int h   = (b >> 2) % HH;
    int n   = b / (4 * HH);
    __shared__ __align__(16) char lds[64 * 128]; // [w 64][ic 64] bf16, swizzled

    int t    = threadIdx.x;
    int w    = t & 63;
    int icl0 = t >> 6;          // 0..3
    if (w < WW) {
        const float* src = x + ((size_t)(n * CIN + icb * 64 + icl0) * HH + h) * WW + w;
#pragma unroll
        for (int j = 0; j < 16; ++j) {
            float v = src[(size_t)(j * 4) * PIXIMG];
            int icl = icl0 + j * 4;
            *(unsigned short*)(lds + w * 128 + ((icl * 2) ^ ((w & 7) << 4))) = f2bf(v);
        }
    }
    __syncthreads();
    int ic4 = t & 15;
    int wr  = t >> 4;
    unsigned short* dst = xt + (size_t)((n * HP + h + 1) * WP + 1) * CIN + icb * 64 + ic4 * 4;
#pragma unroll
    for (int p = 0; p < 4; ++p) {
        int w2 = wr + p * 16;
        if (w2 < WW) {
            uint2 v = *(const uint2*)(lds + w2 * 128 + ((ic4 * 8) ^ ((w2 & 7) << 4)));
            *(uint2*)(dst + (size_t)w2 * CIN) = v;
        }
    }
}

// ---------------------------------------------------------------------------
// wt[tap][oc][ic] = bf16(weight * mask)
// ---------------------------------------------------------------------------
__global__ __launch_bounds__(256) void k_prepw(const float* __restrict__ wgt,
                                               const float* __restrict__ msk,
                                               unsigned short* __restrict__ wt) {
    int t = blockIdx.x * 256 + threadIdx.x; // t = oc*256 + ic
    const float* wp = wgt + (size_t)t * 9;
    const float* mp = msk + (size_t)t * 9;
#pragma unroll
    for (int tap = 0; tap < 9; ++tap)
        wt[(size_t)tap * (COUT * CIN) + t] = f2bf(wp[tap] * mp[tap]);
}

// ---------------------------------------------------------------------------
// Main conv: 9 shifted GEMMs, 2-phase pipelined (double-buffered LDS,
// global_load_lds staging with pre-swizzled sources, 1 barrier per K-step).
// Block tile 128 oc x 128 pix, 4 waves (2x2), BK=64, 16x16x32 bf16 MFMA.
// 36 K-steps = 9 taps x 4 ic-blocks.
// ---------------------------------------------------------------------------
__global__ __launch_bounds__(256) void k_conv(const unsigned short* __restrict__ xt,
                                              const unsigned short* __restrict__ wt,
                                              float* __restrict__ out) {
    // LDS map: A0 @0, B0 @16384, A1 @32768, B1 @49152 (16 KB each, swizzled
    // [row128][64ic]); epilogue aliases whole array as float ep[128][132].
    __shared__ __align__(16) char lds[128 * 132 * 4]; // 67584 B

    const int t    = threadIdx.x;
    const int lane = t & 63;
    const int wid  = t >> 6;
    const int woc  = wid >> 1; // 64-oc half
    const int wpx  = wid & 1;  // 64-pix half

    // XCD-aware chunked swizzle: 1568 blocks = 8 XCDs x 196
    const int b0 = blockIdx.x;
    const int b  = (b0 & 7) * 196 + (b0 >> 3);
    const int ptile = b >> 1;
    const int ocb   = b & 1;

    // ---- staging addresses (wave w stages rows [w*32, w*32+32)) ----
    const int srow8 = lane >> 3;                        // row within 8-row group
    const int sc    = ((lane & 7) ^ srow8) << 3;        // pre-swizzled src col (elems)

    const unsigned short* aS[4];
    const unsigned short* bS[4];
    char* dA[4];
    char* dB[4];
#pragma unroll
    for (int c = 0; c < 4; ++c) {
        int r = wid * 32 + c * 8 + srow8;
        aS[c] = wt + (size_t)(ocb * 128 + r) * CIN + sc;
        int pg  = ptile * 128 + r;
        int n   = pg / PIXIMG;
        int rem = pg - n * PIXIMG;
        int h   = rem / WW, w = rem - h * WW;
        bS[c] = xt + (size_t)((n * HP + h) * WP + w) * CIN + sc;
        dA[c] = lds + (wid * 32 + c * 8) * 128;
        dB[c] = lds + 16384 + (wid * 32 + c * 8) * 128;
    }

    // ---- fragment read offsets ----
    const int l15  = lane & 15;
    const int lg   = lane >> 4;
    const int swzf = (lane & 7) << 4;
    int colk[2];
    colk[0] = (lg * 16) ^ swzf;
    colk[1] = (64 + lg * 16) ^ swzf;
    int rowA[4], rowB[4];
#pragma unroll
    for (int i = 0; i < 4; ++i) {
        rowA[i] = (woc * 64 + i * 16 + l15) * 128;
        rowB[i] = (wpx * 64 + i * 16 + l15) * 128;
    }

    float4v acc[4][4];
#pragma unroll
    for (int i = 0; i < 4; ++i)
#pragma unroll
        for (int j = 0; j < 4; ++j)
            acc[i][j] = (float4v){0.f, 0.f, 0.f, 0.f};

#define STAGE(BUFOFF, S)                                                     \
    do {                                                                     \
        int tap_ = (S) >> 2, ics_ = (S) & 3;                                 \
        int dh_  = (tap_ * 86) >> 8;                                         \
        int dw_  = tap_ - dh_ * 3;                                           \
        size_t ao_ = (size_t)tap_ * (COUT * CIN) + ics_ * 64;                \
        size_t bo_ = (size_t)(dh_ * WP + dw_) * CIN + ics_ * 64;             \
        _Pragma("unroll")                                                    \
        for (int c_ = 0; c_ < 4; ++c_)                                       \
            gl16(aS[c_] + ao_, dA[c_] + (BUFOFF));                           \
        _Pragma("unroll")                                                    \
        for (int c_ = 0; c_ < 4; ++c_)                                       \
            gl16(bS[c_] + bo_, dB[c_] + (BUFOFF));                           \
    } while (0)

#define COMPUTE(BUFOFF)                                                      \
    do {                                                                     \
        _Pragma("unroll")                                                    \
        for (int kk_ = 0; kk_ < 2; ++kk_) {                                  \
            short8 af_[4], bf_[4];                                           \
            _Pragma("unroll")                                                \
            for (int i_ = 0; i_ < 4; ++i_)                                   \
                af_[i_] = *(const short8*)(lds + (BUFOFF) + rowA[i_] + colk[kk_]); \
            _Pragma("unroll")                                                \
            for (int i_ = 0; i_ < 4; ++i_)                                   \
                bf_[i_] = *(const short8*)(lds + (BUFOFF) + 16384 + rowB[i_] + colk[kk_]); \
            _Pragma("unroll")                                                \
            for (int oi_ = 0; oi_ < 4; ++oi_)                                \
                _Pragma("unroll")                                            \
                for (int pi_ = 0; pi_ < 4; ++pi_)                            \
                    acc[oi_][pi_] = __builtin_amdgcn_mfma_f32_16x16x32_bf16( \
                        af_[oi_], bf_[pi_], acc[oi_][pi_], 0, 0, 0);         \
        }                                                                    \
    } while (0)

    // prologue: stage step 0 into buf0
    STAGE(0, 0);
    __syncthreads(); // implicit vmcnt(0) drain + barrier

    // 18 double-iterations, static buffer offsets (no runtime cur indexing)
#pragma unroll 1
    for (int it = 0; it < 18; ++it) {
        int s1 = 2 * it + 1;
        STAGE(32768, s1);      // stage odd step into buf1
        COMPUTE(0);            // compute even step from buf0
        __syncthreads();
        int s2 = 2 * it + 2;
        if (s2 < 36)
            STAGE(0, s2);      // stage next even step into buf0
        COMPUTE(32768);        // compute odd step from buf1
        __syncthreads();
    }
#undef STAGE
#undef COMPUTE

    // ---- epilogue: LDS transpose -> fully coalesced 512B row stores ----
    float* ep = (float*)lds; // [oc 128][pix 132] (pad 4 kills write conflicts)
#pragma unroll
    for (int oi = 0; oi < 4; ++oi)
#pragma unroll
        for (int pi = 0; pi < 4; ++pi)
#pragma unroll
            for (int r = 0; r < 4; ++r)
                ep[(woc * 64 + oi * 16 + lg * 4 + r) * 132 +
                   (wpx * 64 + pi * 16 + l15)] = acc[oi][pi][r];
    __syncthreads();

    const int rrow = t >> 5;        // 0..7
    const int rcol = (t & 31) * 4;  // 0..124
    {
        int pg  = ptile * 128 + rcol;
        int n   = pg / PIXIMG;
        int rem = pg - n * PIXIMG;  // 3136 % 4 == 0: float4 never crosses image
        float* ob = out + (size_t)n * OUTSTRIDE_N + (size_t)(ocb * 128) * PIXIMG + rem;
#pragma unroll
        for (int rd = 0; rd < 16; ++rd) {
            int row = rd * 8 + rrow;
            float4v v = *(const float4v*)&ep[row * 132 + rcol];
            *(float4v*)(ob + (size_t)row * PIXIMG) = v;
        }
    }
}

// ---------------------------------------------------------------------------
// Fallback (ws too small): direct fp32 conv, slow but correct
// ---------------------------------------------------------------------------
__global__ __launch_bounds__(256) void k_naive(const float* __restrict__ x,
                                               const float* __restrict__ wg,
                                               const float* __restrict__ mk,
                                               float* __restrict__ out, int total) {
    int idx = blockIdx.x * 256 + threadIdx.x;
    if (idx >= total) return;
    int w  = idx % WW;
    int h  = (idx / WW) % HH;
    int oc = (idx / PIXIMG) % COUT;
    int n  = idx / (COUT * PIXIMG);
    float s = 0.f;
    for (int ic = 0; ic < CIN; ++ic) {
        const float* xp = x + (size_t)(n * CIN + ic) * PIXIMG;
        const float* wp = wg + (size_t)(oc * CIN + ic) * 9;
        const float* mp = mk + (size_t)(oc * CIN + ic) * 9;
#pragma unroll
        for (int kh = 0; kh < 3; ++kh) {
            int hy = h + kh - 1;
            if ((unsigned)hy >= HH) continue;
#pragma unroll
            for (int kw = 0; kw < 3; ++kw) {
                int wx = w + kw - 1;
                if ((unsigned)wx >= WW) continue;
                s += xp[hy * WW + wx] * wp[kh * 3 + kw] * mp[kh * 3 + kw];
            }
        }
    }
    out[idx] = s;
}

extern "C" void kernel_launch(void* const* d_in, const int* in_sizes, int n_in,
                              void* d_out, int out_size, void* d_ws, size_t ws_size,
                              hipStream_t stream) {
    const float* x  = (const float*)d_in[0];
    const float* wg = (const float*)d_in[1];
    const float* mk = (const float*)d_in[2];
    float* out = (float*)d_out;

    size_t need = XT_ELEMS * 2 + WT_ELEMS * 2 + 256;
    if (ws_size < need) {
        int total = NIMG * COUT * PIXIMG;
        k_naive<<<(total + 255) / 256, 256, 0, stream>>>(x, wg, mk, out, total);
        return;
    }

    unsigned short* xt = (unsigned short*)d_ws;
    unsigned short* wt = (unsigned short*)((char*)d_ws + XT_ELEMS * 2);

    hipMemsetAsync(d_ws, 0, XT_ELEMS * 2, stream); // zero padded halo
    k_transpose<<<NIMG * HH * 4, 256, 0, stream>>>(x, xt);
    k_prepw<<<(COUT * CIN) / 256, 256, 0, stream>>>(wg, mk, wt);
    k_conv<<<(TOTPIX / 128) * 2, 256, 0, stream>>>(xt, wt, out);
}